// Round 8
// baseline (272.949 us; speedup 1.0000x reference)
//
#include <hip/hip_runtime.h>
#include <hip/hip_bf16.h>
#include <cstdint>

#define NN 50000
#define NE 1200000
#define DD 128
#define RR 6
#define NEG 0.2f
#define NB 196          // ceil(NN/256) buckets of 256 nodes
#define TILE 2048       // edges per k_bscatter block

typedef __hip_bfloat16 bf16;
typedef __attribute__((ext_vector_type(8))) short short8;
typedef __attribute__((ext_vector_type(4))) float f32x4;

__device__ __forceinline__ float bflo(unsigned u) { return __uint_as_float((u & 0xFFFFu) << 16); }
__device__ __forceinline__ float bfhi(unsigned u) { return __uint_as_float(u & 0xFFFF0000u); }
__device__ __forceinline__ ushort f2b(float v) {  // f32 -> bf16 RTNE
  unsigned b = __float_as_uint(v);
  return (ushort)((b + 0x7FFFu + ((b >> 16) & 1u)) >> 16);
}

// ------- prep: bcnt zero + wq/wk + pack per-relation W into B-frags --------
__global__ __launch_bounds__(256) void k_prep(const float* __restrict__ W,
    const float* __restrict__ qv, const float* __restrict__ kv,
    float* __restrict__ wq, float* __restrict__ wk,
    ushort* __restrict__ wp, int* __restrict__ bcnt) {
  int t = blockIdx.x * 256 + threadIdx.x;
  if (t < NB) bcnt[t] = 0;
  if (t < RR * DD) {
    int r = t / DD, d = t % DD;
    const float* row = W + ((size_t)r * DD + d) * DD;
    float aq = 0.f, ak = 0.f;
    for (int o = 0; o < DD; ++o) { float w = row[o]; aq += w * qv[o]; ak += w * kv[o]; }
    wq[t] = aq; wk[t] = ak;
  }
  {
    int lane = t & 63;
    int ks = (t >> 6) & 3;
    int cf = (t >> 8) & 7;
    int r = t >> 11;
    if (r < RR) {
      int col = cf * 16 + (lane & 15);
      int k0 = ks * 32 + (lane >> 4) * 8;
      ushort* dst = wp + (size_t)t * 8;
      #pragma unroll
      for (int e = 0; e < 8; ++e)
        dst[e] = f2b(W[((size_t)r * DD + (k0 + e)) * DD + col]);
    }
  }
}

// ---------------- nq[r,n] = x[n]·wq[r], one wave per node -----------------
__global__ __launch_bounds__(256) void k_nqk(const float* __restrict__ x,
    const float* __restrict__ wq, const float* __restrict__ wk,
    float* __restrict__ nq, float* __restrict__ nk) {
  int w = threadIdx.x >> 6, lane = threadIdx.x & 63;
  int n = blockIdx.x * 4 + w;
  if (n >= NN) return;
  float x0 = x[(size_t)n * DD + lane];
  float x1 = x[(size_t)n * DD + 64 + lane];
  for (int r = 0; r < RR; ++r) {
    float pq = x0 * wq[r * DD + lane] + x1 * wq[r * DD + 64 + lane];
    float pk = x0 * wk[r * DD + lane] + x1 * wk[r * DD + 64 + lane];
    #pragma unroll
    for (int m = 32; m > 0; m >>= 1) { pq += __shfl_xor(pq, m); pk += __shfl_xor(pk, m); }
    if (lane == 0) { nq[r * NN + n] = pq; nk[r * NN + n] = pk; }
  }
}

// ---------------- hx[r,n,o] via bf16 MFMA; A regs reused over relations ---
__global__ __launch_bounds__(256) void k_gemm(const float* __restrict__ x,
    const ushort* __restrict__ wp, ushort* __restrict__ hx) {
  int tid = threadIdx.x;
  int w = tid >> 6, l = tid & 63;
  int wrow = w & 1, wcol = w >> 1;
  int row0 = blockIdx.x * 64 + wrow * 32;
  int lr = l & 15, lg = l >> 4;

  short8 af[2][4];
  #pragma unroll
  for (int rf = 0; rf < 2; ++rf) {
    int row = row0 + rf * 16 + lr;
    row = row < NN ? row : NN - 1;
    const float* src = x + (size_t)row * DD + lg * 8;
    #pragma unroll
    for (int ks = 0; ks < 4; ++ks) {
      float4 u0 = *reinterpret_cast<const float4*>(src + ks * 32);
      float4 u1 = *reinterpret_cast<const float4*>(src + ks * 32 + 4);
      short8 a;
      a[0] = (short)f2b(u0.x); a[1] = (short)f2b(u0.y);
      a[2] = (short)f2b(u0.z); a[3] = (short)f2b(u0.w);
      a[4] = (short)f2b(u1.x); a[5] = (short)f2b(u1.y);
      a[6] = (short)f2b(u1.z); a[7] = (short)f2b(u1.w);
      af[rf][ks] = a;
    }
  }

  for (int r = 0; r < RR; ++r) {
    #pragma unroll
    for (int cfl = 0; cfl < 4; ++cfl) {
      int cfg = wcol * 4 + cfl;
      const ushort* bp = wp + (((size_t)(r * 8 + cfg) * 4) * 64 + l) * 8;
      short8 b0 = *reinterpret_cast<const short8*>(bp);
      short8 b1 = *reinterpret_cast<const short8*>(bp + 512);
      short8 b2 = *reinterpret_cast<const short8*>(bp + 1024);
      short8 b3 = *reinterpret_cast<const short8*>(bp + 1536);
      f32x4 acc0 = {0.f, 0.f, 0.f, 0.f};
      f32x4 acc1 = {0.f, 0.f, 0.f, 0.f};
      acc0 = __builtin_amdgcn_mfma_f32_16x16x32_bf16(af[0][0], b0, acc0, 0, 0, 0);
      acc1 = __builtin_amdgcn_mfma_f32_16x16x32_bf16(af[1][0], b0, acc1, 0, 0, 0);
      acc0 = __builtin_amdgcn_mfma_f32_16x16x32_bf16(af[0][1], b1, acc0, 0, 0, 0);
      acc1 = __builtin_amdgcn_mfma_f32_16x16x32_bf16(af[1][1], b1, acc1, 0, 0, 0);
      acc0 = __builtin_amdgcn_mfma_f32_16x16x32_bf16(af[0][2], b2, acc0, 0, 0, 0);
      acc1 = __builtin_amdgcn_mfma_f32_16x16x32_bf16(af[1][2], b2, acc1, 0, 0, 0);
      acc0 = __builtin_amdgcn_mfma_f32_16x16x32_bf16(af[0][3], b3, acc0, 0, 0, 0);
      acc1 = __builtin_amdgcn_mfma_f32_16x16x32_bf16(af[1][3], b3, acc1, 0, 0, 0);

      int col = cfg * 16 + lr;
      #pragma unroll
      for (int rf = 0; rf < 2; ++rf) {
        int rowb = row0 + rf * 16 + lg * 4;
        f32x4 ac = rf ? acc1 : acc0;
        #pragma unroll
        for (int j = 0; j < 4; ++j) {
          int rowz = rowb + j;
          if (rowz < NN)
            hx[((size_t)r * NN + rowz) * DD + col] = f2b(ac[j]);
        }
      }
    }
  }
}

// ---------------- bucket histogram (LDS-staged) ----------------------------
__global__ __launch_bounds__(256) void k_histb(const int* __restrict__ ei,
                                               int* __restrict__ bcnt) {
  __shared__ int lh[NB];
  int tid = threadIdx.x;
  if (tid < NB) lh[tid] = 0;
  __syncthreads();
  int e = blockIdx.x * 1024 + tid;
  #pragma unroll
  for (int k = 0; k < 4; ++k, e += 256)
    if (e < NE) atomicAdd(&lh[ei[NE + e] >> 8], 1);
  __syncthreads();
  if (tid < NB && lh[tid]) atomicAdd(&bcnt[tid], lh[tid]);
}

// ---------------- bucket base scan + zero cursors --------------------------
__global__ __launch_bounds__(64) void k_bscan(const int* __restrict__ bcnt,
    int* __restrict__ bbase, int* __restrict__ bcur) {
  if (threadIdx.x == 0) {
    int run = 0;
    for (int i = 0; i < NB; ++i) { bbase[i] = run; bcur[i] = 0; run += bcnt[i]; }
  }
}

// ------- partition edges into bucket-grouped bedge, with PRECOMPUTED logit -
// bedge.x = rowid(19b) | dlo<<19 ; bedge.y = logit bits
__global__ __launch_bounds__(256) void k_bscatter(const int* __restrict__ ei,
    const int* __restrict__ et, const float* __restrict__ nq,
    const float* __restrict__ nk, const int* __restrict__ bbase,
    int* __restrict__ bcur, uint2* __restrict__ bedge) {
  __shared__ uint2 sval[TILE];
  __shared__ unsigned char sbkt[TILE];
  __shared__ int lh[NB], lbase[NB], lcur[NB];
  int tid = threadIdx.x;
  int e0 = blockIdx.x * TILE;
  int lim = NE - e0; if (lim > TILE) lim = TILE;
  for (int i = tid; i < NB; i += 256) lh[i] = 0;
  __syncthreads();
  for (int i = tid; i < lim; i += 256) {
    int e = e0 + i;
    int s = ei[e], d = ei[NE + e], r = et[e];
    float l = nq[r * NN + d] + nk[r * NN + s];
    l = l > 0.f ? l : NEG * l;
    sval[i] = make_uint2((unsigned)(r * NN + s) | ((unsigned)(d & 255) << 19),
                         __float_as_uint(l));
    sbkt[i] = (unsigned char)(d >> 8);
    atomicAdd(&lh[d >> 8], 1);
  }
  __syncthreads();
  for (int i = tid; i < NB; i += 256) {
    int c = lh[i];
    lbase[i] = c ? atomicAdd(&bcur[i], c) : 0;
    lcur[i] = 0;
  }
  __syncthreads();
  for (int i = tid; i < lim; i += 256) {
    int b = sbkt[i];
    int pos = bbase[b] + lbase[b] + atomicAdd(&lcur[b], 1);
    bedge[pos] = sval[i];
  }
}

// ------- per-bucket: deg, offs, CSR placement (L2-local writes) ------------
// rec.x = byte offset into hx (rowid*256) ; rec.y = logit bits
__global__ __launch_bounds__(256) void k_bfinal(const uint2* __restrict__ bedge,
    const int* __restrict__ bbase, const int* __restrict__ bcnt,
    int* __restrict__ deg, int* __restrict__ offs, uint2* __restrict__ rec) {
  __shared__ int lh[256], sc[256], lcur[256];
  int b = blockIdx.x, tid = threadIdx.x;
  int base = bbase[b], cnt = bcnt[b];
  lh[tid] = 0;
  __syncthreads();
  for (int i = tid; i < cnt; i += 256)
    atomicAdd(&lh[(bedge[base + i].x >> 19) & 255], 1);
  __syncthreads();
  int v = lh[tid];
  sc[tid] = v;
  __syncthreads();
  for (int off = 1; off < 256; off <<= 1) {
    int u = (tid >= off) ? sc[tid - off] : 0;
    __syncthreads();
    sc[tid] += u;
    __syncthreads();
  }
  int excl = sc[tid] - v;
  int n = (b << 8) + tid;
  if (n < NN) { deg[n] = v; offs[n] = base + excl; }
  lcur[tid] = base + excl;
  __syncthreads();
  for (int i = tid; i < cnt; i += 256) {
    uint2 r = bedge[base + i];
    int pos = atomicAdd(&lcur[(r.x >> 19) & 255], 1);
    rec[pos] = make_uint2((r.x & 0x7FFFFu) << 8, r.y);
  }
}

// ------- fused online-softmax gather-aggregate (precomputed logits) --------
__global__ __launch_bounds__(256) void k_agg(const float* __restrict__ x,
    const float* __restrict__ bias, const int* __restrict__ offs,
    const int* __restrict__ deg, const uint2* __restrict__ rec,
    const bf16* __restrict__ hx, float* __restrict__ out,
    float* __restrict__ mrec, float* __restrict__ irec) {
  int g = threadIdx.x >> 5, lane = threadIdx.x & 31;
  int n = blockIdx.x * 8 + g;
  if (n >= NN) return;
  int base = offs[n], cnt = deg[n];
  const char* hp = (const char*)hx;
  int lo8 = lane * 8;

  float m = -1e30f, ssum = 0.f;
  float a0 = 0.f, a1 = 0.f, a2 = 0.f, a3 = 0.f;

  int j = 0;
  for (; j + 3 < cnt; j += 4) {
    uint2 e1 = rec[base + j],     e2 = rec[base + j + 1];
    uint2 e3 = rec[base + j + 2], e4 = rec[base + j + 3];
    uint2 q1 = *reinterpret_cast<const uint2*>(hp + e1.x + lo8);
    uint2 q2 = *reinterpret_cast<const uint2*>(hp + e2.x + lo8);
    uint2 q3 = *reinterpret_cast<const uint2*>(hp + e3.x + lo8);
    uint2 q4 = *reinterpret_cast<const uint2*>(hp + e4.x + lo8);
    float l1 = __uint_as_float(e1.y), l2 = __uint_as_float(e2.y);
    float l3 = __uint_as_float(e3.y), l4 = __uint_as_float(e4.y);
    float pm = fmaxf(fmaxf(l1, l2), fmaxf(l3, l4));
    if (pm > m + 8.f) {              // defer-max (T13): rescale rarely
      float sc = __expf(m - pm);
      ssum *= sc; a0 *= sc; a1 *= sc; a2 *= sc; a3 *= sc;
      m = pm;
    }
    float p1 = __expf(l1 - m), p2 = __expf(l2 - m);
    float p3 = __expf(l3 - m), p4 = __expf(l4 - m);
    ssum += (p1 + p2) + (p3 + p4);
    a0 += p1 * bflo(q1.x) + p2 * bflo(q2.x) + p3 * bflo(q3.x) + p4 * bflo(q4.x);
    a1 += p1 * bfhi(q1.x) + p2 * bfhi(q2.x) + p3 * bfhi(q3.x) + p4 * bfhi(q4.x);
    a2 += p1 * bflo(q1.y) + p2 * bflo(q2.y) + p3 * bflo(q3.y) + p4 * bflo(q4.y);
    a3 += p1 * bfhi(q1.y) + p2 * bfhi(q2.y) + p3 * bfhi(q3.y) + p4 * bfhi(q4.y);
  }
  for (; j < cnt; ++j) {
    uint2 e1 = rec[base + j];
    uint2 q1 = *reinterpret_cast<const uint2*>(hp + e1.x + lo8);
    float l1 = __uint_as_float(e1.y);
    if (l1 > m + 8.f) {
      float sc = __expf(m - l1);
      ssum *= sc; a0 *= sc; a1 *= sc; a2 *= sc; a3 *= sc;
      m = l1;
    }
    float p1 = __expf(l1 - m);
    ssum += p1;
    a0 += p1 * bflo(q1.x);
    a1 += p1 * bfhi(q1.x);
    a2 += p1 * bflo(q1.y);
    a3 += p1 * bfhi(q1.y);
  }

  float inv = 1.f / (ssum + 1e-16f);
  size_t o = (size_t)n * DD + lane * 4;
  float4 xb = *reinterpret_cast<const float4*>(x + o);
  float4 bb = *reinterpret_cast<const float4*>(bias + lane * 4);
  float4 res;
  res.x = xb.x + bb.x + a0 * inv;
  res.y = xb.y + bb.y + a1 * inv;
  res.z = xb.z + bb.z + a2 * inv;
  res.w = xb.w + bb.w + a3 * inv;
  *reinterpret_cast<float4*>(out + o) = res;

  if (lane == 0) { mrec[n] = m; irec[n] = inv; }
}

// ---------------- alpha in original edge order (coalesced write) -----------
__global__ __launch_bounds__(256) void k_alpha(const int* __restrict__ ei,
    const int* __restrict__ et, const float* __restrict__ nq,
    const float* __restrict__ nk, const float* __restrict__ mrec,
    const float* __restrict__ irec, float* __restrict__ alpha) {
  int e = blockIdx.x * 256 + threadIdx.x;
  if (e >= NE) return;
  int s = ei[e], d = ei[NE + e], r = et[e];
  float l = nq[r * NN + d] + nk[r * NN + s];
  l = l > 0.f ? l : NEG * l;
  alpha[e] = __expf(l - mrec[d]) * irec[d];
}

extern "C" void kernel_launch(void* const* d_in, const int* in_sizes, int n_in,
                              void* d_out, int out_size, void* d_ws, size_t ws_size,
                              hipStream_t stream) {
  const float* x    = (const float*)d_in[0];
  const int*   ei   = (const int*)d_in[1];
  const int*   et   = (const int*)d_in[2];
  const float* W    = (const float*)d_in[3];
  const float* qv   = (const float*)d_in[4];
  const float* kv   = (const float*)d_in[5];
  const float* bias = (const float*)d_in[6];

  float* out   = (float*)d_out;              // [NN*DD]
  float* alpha = out + (size_t)NN * DD;      // [NE]

  char* p = (char*)d_ws;
  bf16*  hx      = (bf16*)p;    p += (size_t)RR * NN * DD * sizeof(bf16); // 76.8 MB
  float* nq      = (float*)p;   p += (size_t)RR * NN * sizeof(float);
  float* nk      = (float*)p;   p += (size_t)RR * NN * sizeof(float);
  float* wq      = (float*)p;   p += RR * DD * sizeof(float);
  float* wk      = (float*)p;   p += RR * DD * sizeof(float);
  int*   deg     = (int*)p;     p += NN * sizeof(int);
  int*   offs    = (int*)p;     p += NN * sizeof(int);
  float* mrec    = (float*)p;   p += NN * sizeof(float);
  float* irec    = (float*)p;   p += NN * sizeof(float);
  int*   bcnt    = (int*)p;     p += NB * sizeof(int);
  int*   bbase   = (int*)p;     p += NB * sizeof(int);
  int*   bcur    = (int*)p;     p += NB * sizeof(int);
  p = (char*)(((uintptr_t)p + 15) & ~(uintptr_t)15);
  uint2* bedge   = (uint2*)p;   p += (size_t)NE * sizeof(uint2);          // 9.6 MB
  uint2* rec     = (uint2*)p;   p += (size_t)NE * sizeof(uint2);          // 9.6 MB
  ushort* wp     = (ushort*)p;  p += (size_t)RR * 8 * 4 * 64 * 8 * sizeof(ushort); // 196 KB

  k_prep<<<48, 256, 0, stream>>>(W, qv, kv, wq, wk, wp, bcnt);
  k_gemm<<<(NN + 63) / 64, 256, 0, stream>>>(x, wp, (ushort*)hx);
  k_nqk<<<(NN + 3) / 4, 256, 0, stream>>>(x, wq, wk, nq, nk);
  k_histb<<<(NE + 1023) / 1024, 256, 0, stream>>>(ei, bcnt);
  k_bscan<<<1, 64, 0, stream>>>(bcnt, bbase, bcur);
  k_bscatter<<<(NE + TILE - 1) / TILE, 256, 0, stream>>>(ei, et, nq, nk,
                                                         bbase, bcur, bedge);
  k_bfinal<<<NB, 256, 0, stream>>>(bedge, bbase, bcnt, deg, offs, rec);
  k_agg<<<(NN + 7) / 8, 256, 0, stream>>>(x, bias, offs, deg, rec,
                                          hx, out, mrec, irec);
  k_alpha<<<(NE + 255) / 256, 256, 0, stream>>>(ei, et, nq, nk, mrec, irec, alpha);
}

// Round 9
// 230.972 us; speedup vs baseline: 1.1817x; 1.1817x over previous
//
#include <hip/hip_runtime.h>
#include <hip/hip_bf16.h>
#include <cstdint>

#define NN 50000
#define NE 1200000
#define DD 128
#define RR 6
#define NEG 0.2f
#define NB 391          // ceil(NN/128) buckets of 128 nodes
#define TILE 4096       // edges per k_bscatter block

typedef __hip_bfloat16 bf16;
typedef __attribute__((ext_vector_type(8))) short short8;
typedef __attribute__((ext_vector_type(4))) float f32x4;

__device__ __forceinline__ float bflo(unsigned u) { return __uint_as_float(u << 16); }
__device__ __forceinline__ float bfhi(unsigned u) { return __uint_as_float(u & 0xFFFF0000u); }
__device__ __forceinline__ ushort f2b(float v) {  // f32 -> bf16 RTNE
  unsigned b = __float_as_uint(v);
  return (ushort)((b + 0x7FFFu + ((b >> 16) & 1u)) >> 16);
}

// ------- prep: bcnt zero + wq/wk + W B-frags + wq/wk B-frag (wp7) ----------
__global__ __launch_bounds__(256) void k_prep(const float* __restrict__ W,
    const float* __restrict__ qv, const float* __restrict__ kv,
    float* __restrict__ wq, float* __restrict__ wk,
    ushort* __restrict__ wp, ushort* __restrict__ wp7, int* __restrict__ bcnt) {
  int t = blockIdx.x * 256 + threadIdx.x;
  if (t < NB) bcnt[t] = 0;
  if (t < RR * DD) {
    int r = t / DD, d = t % DD;
    const float* row = W + ((size_t)r * DD + d) * DD;
    float aq = 0.f, ak = 0.f;
    for (int o = 0; o < DD; ++o) { float w = row[o]; aq += w * qv[o]; ak += w * kv[o]; }
    wq[t] = aq; wk[t] = ak;
  }
  if (t < RR * 8 * 4 * 64) {
    int lane = t & 63;
    int ks = (t >> 6) & 3;
    int cf = (t >> 8) & 7;
    int r = t >> 11;
    int col = cf * 16 + (lane & 15);
    int k0 = ks * 32 + (lane >> 4) * 8;
    ushort* dst = wp + (size_t)t * 8;
    #pragma unroll
    for (int e = 0; e < 8; ++e)
      dst[e] = f2b(W[((size_t)r * DD + (k0 + e)) * DD + col]);
  } else if (t < RR * 8 * 4 * 64 + 256) {
    // wp7: B[k][col] with col<6 -> (W_col q)[k], col in 6..11 -> (W_(col-6) k)[k]
    int idx = t - RR * 8 * 4 * 64;
    int lane = idx & 63, ks = idx >> 6;
    int col = lane & 15;
    int k0 = ks * 32 + (lane >> 4) * 8;
    ushort* dst = wp7 + (size_t)idx * 8;
    #pragma unroll
    for (int e = 0; e < 8; ++e) {
      float v = 0.f;
      if (col < 12) {
        int r = col < 6 ? col : col - 6;
        const float* vv = col < 6 ? qv : kv;
        const float* row = W + ((size_t)r * DD + (k0 + e)) * DD;
        for (int o = 0; o < DD; ++o) v += row[o] * vv[o];
      }
      dst[e] = f2b(v);
    }
  }
}

// ---- hx via bf16 MFMA (LDS-staged coalesced store) + fused nq/nk MFMA ----
__global__ __launch_bounds__(256) void k_gemm(const float* __restrict__ x,
    const ushort* __restrict__ wp, const ushort* __restrict__ wp7,
    ushort* __restrict__ hx, float* __restrict__ nq, float* __restrict__ nk) {
  __shared__ ushort tile[64][136];
  int tid = threadIdx.x;
  int w = tid >> 6, l = tid & 63;
  int wrow = w & 1, wcol = w >> 1;
  int row0 = blockIdx.x * 64;
  int rbase = row0 + wrow * 32;
  int lr = l & 15, lg = l >> 4;

  short8 af[2][4];
  #pragma unroll
  for (int rf = 0; rf < 2; ++rf) {
    int row = rbase + rf * 16 + lr;
    row = row < NN ? row : NN - 1;
    const float* src = x + (size_t)row * DD + lg * 8;
    #pragma unroll
    for (int ks = 0; ks < 4; ++ks) {
      float4 u0 = *reinterpret_cast<const float4*>(src + ks * 32);
      float4 u1 = *reinterpret_cast<const float4*>(src + ks * 32 + 4);
      short8 a;
      a[0] = (short)f2b(u0.x); a[1] = (short)f2b(u0.y);
      a[2] = (short)f2b(u0.z); a[3] = (short)f2b(u0.w);
      a[4] = (short)f2b(u1.x); a[5] = (short)f2b(u1.y);
      a[6] = (short)f2b(u1.z); a[7] = (short)f2b(u1.w);
      af[rf][ks] = a;
    }
  }

  // fused nq/nk: one extra MFMA group (cols 0-5 = nq_r, 6-11 = nk_r)
  if (wcol == 0) {
    f32x4 aq0 = {0.f, 0.f, 0.f, 0.f}, aq1 = {0.f, 0.f, 0.f, 0.f};
    #pragma unroll
    for (int ks = 0; ks < 4; ++ks) {
      short8 b = *reinterpret_cast<const short8*>(wp7 + (size_t)(ks * 64 + l) * 8);
      aq0 = __builtin_amdgcn_mfma_f32_16x16x32_bf16(af[0][ks], b, aq0, 0, 0, 0);
      aq1 = __builtin_amdgcn_mfma_f32_16x16x32_bf16(af[1][ks], b, aq1, 0, 0, 0);
    }
    if (lr < 12) {
      float* pl = (lr < 6 ? nq + (size_t)lr * NN : nk + (size_t)(lr - 6) * NN);
      #pragma unroll
      for (int rf = 0; rf < 2; ++rf) {
        int rowb = rbase + rf * 16 + lg * 4;
        f32x4 v = rf ? aq1 : aq0;
        if (rowb + 3 < NN) {
          float4 o4 = make_float4(v[0], v[1], v[2], v[3]);
          *reinterpret_cast<float4*>(pl + rowb) = o4;
        } else {
          #pragma unroll
          for (int j = 0; j < 4; ++j) if (rowb + j < NN) pl[rowb + j] = v[j];
        }
      }
    }
  }

  for (int r = 0; r < RR; ++r) {
    #pragma unroll
    for (int cfl = 0; cfl < 4; ++cfl) {
      int cfg = wcol * 4 + cfl;
      const ushort* bp = wp + (((size_t)(r * 8 + cfg) * 4) * 64 + l) * 8;
      short8 b0 = *reinterpret_cast<const short8*>(bp);
      short8 b1 = *reinterpret_cast<const short8*>(bp + 512);
      short8 b2 = *reinterpret_cast<const short8*>(bp + 1024);
      short8 b3 = *reinterpret_cast<const short8*>(bp + 1536);
      f32x4 acc0 = {0.f, 0.f, 0.f, 0.f};
      f32x4 acc1 = {0.f, 0.f, 0.f, 0.f};
      acc0 = __builtin_amdgcn_mfma_f32_16x16x32_bf16(af[0][0], b0, acc0, 0, 0, 0);
      acc1 = __builtin_amdgcn_mfma_f32_16x16x32_bf16(af[1][0], b0, acc1, 0, 0, 0);
      acc0 = __builtin_amdgcn_mfma_f32_16x16x32_bf16(af[0][1], b1, acc0, 0, 0, 0);
      acc1 = __builtin_amdgcn_mfma_f32_16x16x32_bf16(af[1][1], b1, acc1, 0, 0, 0);
      acc0 = __builtin_amdgcn_mfma_f32_16x16x32_bf16(af[0][2], b2, acc0, 0, 0, 0);
      acc1 = __builtin_amdgcn_mfma_f32_16x16x32_bf16(af[1][2], b2, acc1, 0, 0, 0);
      acc0 = __builtin_amdgcn_mfma_f32_16x16x32_bf16(af[0][3], b3, acc0, 0, 0, 0);
      acc1 = __builtin_amdgcn_mfma_f32_16x16x32_bf16(af[1][3], b3, acc1, 0, 0, 0);

      int col = cfg * 16 + lr;
      #pragma unroll
      for (int rf = 0; rf < 2; ++rf) {
        int rowrel = wrow * 32 + rf * 16 + lg * 4;
        f32x4 ac = rf ? acc1 : acc0;
        #pragma unroll
        for (int j = 0; j < 4; ++j)
          tile[rowrel + j][col] = f2b(ac[j]);
      }
    }
    __syncthreads();
    // coalesced copy-out: 16 lanes cover one 256B row, 1KB/instr per wave
    #pragma unroll
    for (int it = 0; it < 4; ++it) {
      int rowrel = (tid >> 4) + it * 16;
      int grow = row0 + rowrel;
      uint4 v = *reinterpret_cast<const uint4*>(&tile[rowrel][(tid & 15) * 8]);
      if (grow < NN)
        *reinterpret_cast<uint4*>(hx + ((size_t)r * NN + grow) * DD + (tid & 15) * 8) = v;
    }
    __syncthreads();
  }
}

// ---------------- bucket histogram (LDS-staged) ----------------------------
__global__ __launch_bounds__(256) void k_histb(const int* __restrict__ ei,
                                               int* __restrict__ bcnt) {
  __shared__ int lh[NB];
  int tid = threadIdx.x;
  for (int i = tid; i < NB; i += 256) lh[i] = 0;
  __syncthreads();
  int e = blockIdx.x * 1024 + tid;
  #pragma unroll
  for (int k = 0; k < 4; ++k, e += 256)
    if (e < NE) atomicAdd(&lh[ei[NE + e] >> 7], 1);
  __syncthreads();
  for (int i = tid; i < NB; i += 256)
    if (lh[i]) atomicAdd(&bcnt[i], lh[i]);
}

// ---------------- bucket base scan + zero cursors --------------------------
__global__ __launch_bounds__(64) void k_bscan(const int* __restrict__ bcnt,
    int* __restrict__ bbase, int* __restrict__ bcur) {
  if (threadIdx.x == 0) {
    int run = 0;
    for (int i = 0; i < NB; ++i) { bbase[i] = run; bcur[i] = 0; run += bcnt[i]; }
  }
}

// ------- partition edges: bedge = rowid<<3 | r | dlo<<22 -------------------
__global__ __launch_bounds__(256) void k_bscatter(const int* __restrict__ ei,
    const int* __restrict__ et, const int* __restrict__ bbase,
    int* __restrict__ bcur, unsigned* __restrict__ bedge) {
  __shared__ unsigned sval[TILE];
  __shared__ unsigned short sbkt[TILE];
  __shared__ int lh[NB], lbase[NB], lcur[NB];
  int tid = threadIdx.x;
  int e0 = blockIdx.x * TILE;
  int lim = NE - e0; if (lim > TILE) lim = TILE;
  for (int i = tid; i < NB; i += 256) lh[i] = 0;
  __syncthreads();
  for (int i = tid; i < lim; i += 256) {
    int e = e0 + i;
    int s = ei[e], d = ei[NE + e], r = et[e];
    unsigned rowid = (unsigned)(r * NN + s);
    sval[i] = (rowid << 3) | (unsigned)r | ((unsigned)(d & 127) << 22);
    sbkt[i] = (unsigned short)(d >> 7);
    atomicAdd(&lh[d >> 7], 1);
  }
  __syncthreads();
  for (int i = tid; i < NB; i += 256) {
    int c = lh[i];
    lbase[i] = c ? atomicAdd(&bcur[i], c) : 0;
    lcur[i] = 0;
  }
  __syncthreads();
  for (int i = tid; i < lim; i += 256) {
    int b = sbkt[i];
    int pos = bbase[b] + lbase[b] + atomicAdd(&lcur[b], 1);
    bedge[pos] = sval[i];
  }
}

// ------- per-bucket (128 nodes): deg, offs, CSR rec = rowid<<8 | r ---------
__global__ __launch_bounds__(128) void k_bfinal(const unsigned* __restrict__ bedge,
    const int* __restrict__ bbase, const int* __restrict__ bcnt,
    int* __restrict__ deg, int* __restrict__ offs, unsigned* __restrict__ rec) {
  __shared__ int lh[128], sc[128], lcur[128];
  int b = blockIdx.x, tid = threadIdx.x;
  int base = bbase[b], cnt = bcnt[b];
  lh[tid] = 0;
  __syncthreads();
  for (int i = tid; i < cnt; i += 128)
    atomicAdd(&lh[(bedge[base + i] >> 22) & 127], 1);
  __syncthreads();
  int v = lh[tid];
  sc[tid] = v;
  __syncthreads();
  for (int off = 1; off < 128; off <<= 1) {
    int u = (tid >= off) ? sc[tid - off] : 0;
    __syncthreads();
    sc[tid] += u;
    __syncthreads();
  }
  int excl = sc[tid] - v;
  int n = (b << 7) + tid;
  if (n < NN) { deg[n] = v; offs[n] = base + excl; }
  lcur[tid] = base + excl;
  __syncthreads();
  for (int i = tid; i < cnt; i += 128) {
    unsigned r = bedge[base + i];
    int pos = atomicAdd(&lcur[(r >> 22) & 127], 1);
    rec[pos] = ((r & 0x3FFFF8u) << 5) | (r & 7u);   // rowid<<8 | r
  }
}

// ------- fused online-softmax gather-aggregate ------------------------------
// rec gives hx byte offset directly; nq via preloaded regs + shfl; nk flat
__global__ __launch_bounds__(256) void k_agg(const float* __restrict__ x,
    const float* __restrict__ bias, const int* __restrict__ offs,
    const int* __restrict__ deg, const unsigned* __restrict__ rec,
    const float* __restrict__ nq, const float* __restrict__ nk,
    const bf16* __restrict__ hx, float* __restrict__ out,
    float* __restrict__ mrec, float* __restrict__ irec) {
  int g = threadIdx.x >> 5, lane = threadIdx.x & 31;
  int n = blockIdx.x * 8 + g;
  if (n >= NN) return;
  int base = offs[n], cnt = deg[n];
  const char* hp = (const char*)hx;
  int lo8 = lane * 8;

  float nqv_own = lane < 6 ? nq[(size_t)lane * NN + n] : 0.f;

  float m = -1e30f, ssum = 0.f;
  float a0 = 0.f, a1 = 0.f, a2 = 0.f, a3 = 0.f;

  int j = 0;
  for (; j + 3 < cnt; j += 4) {
    unsigned s1 = rec[base + j],     s2 = rec[base + j + 1];
    unsigned s3 = rec[base + j + 2], s4 = rec[base + j + 3];
    uint2 q1 = *reinterpret_cast<const uint2*>(hp + (s1 & 0xFFFFFF00u) + lo8);
    uint2 q2 = *reinterpret_cast<const uint2*>(hp + (s2 & 0xFFFFFF00u) + lo8);
    uint2 q3 = *reinterpret_cast<const uint2*>(hp + (s3 & 0xFFFFFF00u) + lo8);
    uint2 q4 = *reinterpret_cast<const uint2*>(hp + (s4 & 0xFFFFFF00u) + lo8);
    float l1 = __shfl(nqv_own, (int)(s1 & 7u), 32) + nk[s1 >> 8];
    float l2 = __shfl(nqv_own, (int)(s2 & 7u), 32) + nk[s2 >> 8];
    float l3 = __shfl(nqv_own, (int)(s3 & 7u), 32) + nk[s3 >> 8];
    float l4 = __shfl(nqv_own, (int)(s4 & 7u), 32) + nk[s4 >> 8];
    l1 = l1 > 0.f ? l1 : NEG * l1;  l2 = l2 > 0.f ? l2 : NEG * l2;
    l3 = l3 > 0.f ? l3 : NEG * l3;  l4 = l4 > 0.f ? l4 : NEG * l4;
    float pm = fmaxf(fmaxf(l1, l2), fmaxf(l3, l4));
    if (pm > m + 8.f) {              // defer-max (T13)
      float sc = __expf(m - pm);
      ssum *= sc; a0 *= sc; a1 *= sc; a2 *= sc; a3 *= sc;
      m = pm;
    }
    float p1 = __expf(l1 - m), p2 = __expf(l2 - m);
    float p3 = __expf(l3 - m), p4 = __expf(l4 - m);
    ssum += (p1 + p2) + (p3 + p4);
    a0 += p1 * bflo(q1.x) + p2 * bflo(q2.x) + p3 * bflo(q3.x) + p4 * bflo(q4.x);
    a1 += p1 * bfhi(q1.x) + p2 * bfhi(q2.x) + p3 * bfhi(q3.x) + p4 * bfhi(q4.x);
    a2 += p1 * bflo(q1.y) + p2 * bflo(q2.y) + p3 * bflo(q3.y) + p4 * bflo(q4.y);
    a3 += p1 * bfhi(q1.y) + p2 * bfhi(q2.y) + p3 * bfhi(q3.y) + p4 * bfhi(q4.y);
  }
  for (; j < cnt; ++j) {
    unsigned s1 = rec[base + j];
    uint2 q1 = *reinterpret_cast<const uint2*>(hp + (s1 & 0xFFFFFF00u) + lo8);
    float l1 = __shfl(nqv_own, (int)(s1 & 7u), 32) + nk[s1 >> 8];
    l1 = l1 > 0.f ? l1 : NEG * l1;
    if (l1 > m + 8.f) {
      float sc = __expf(m - l1);
      ssum *= sc; a0 *= sc; a1 *= sc; a2 *= sc; a3 *= sc;
      m = l1;
    }
    float p1 = __expf(l1 - m);
    ssum += p1;
    a0 += p1 * bflo(q1.x);
    a1 += p1 * bfhi(q1.x);
    a2 += p1 * bflo(q1.y);
    a3 += p1 * bfhi(q1.y);
  }

  float inv = 1.f / (ssum + 1e-16f);
  size_t o = (size_t)n * DD + lane * 4;
  float4 xb = *reinterpret_cast<const float4*>(x + o);
  float4 bb = *reinterpret_cast<const float4*>(bias + lane * 4);
  float4 res;
  res.x = xb.x + bb.x + a0 * inv;
  res.y = xb.y + bb.y + a1 * inv;
  res.z = xb.z + bb.z + a2 * inv;
  res.w = xb.w + bb.w + a3 * inv;
  *reinterpret_cast<float4*>(out + o) = res;

  if (lane == 0) { mrec[n] = m; irec[n] = inv; }
}

// ---------------- alpha in original edge order (coalesced write) -----------
__global__ __launch_bounds__(256) void k_alpha(const int* __restrict__ ei,
    const int* __restrict__ et, const float* __restrict__ nq,
    const float* __restrict__ nk, const float* __restrict__ mrec,
    const float* __restrict__ irec, float* __restrict__ alpha) {
  int e = blockIdx.x * 256 + threadIdx.x;
  if (e >= NE) return;
  int s = ei[e], d = ei[NE + e], r = et[e];
  float l = nq[r * NN + d] + nk[r * NN + s];
  l = l > 0.f ? l : NEG * l;
  alpha[e] = __expf(l - mrec[d]) * irec[d];
}

extern "C" void kernel_launch(void* const* d_in, const int* in_sizes, int n_in,
                              void* d_out, int out_size, void* d_ws, size_t ws_size,
                              hipStream_t stream) {
  const float* x    = (const float*)d_in[0];
  const int*   ei   = (const int*)d_in[1];
  const int*   et   = (const int*)d_in[2];
  const float* W    = (const float*)d_in[3];
  const float* qv   = (const float*)d_in[4];
  const float* kv   = (const float*)d_in[5];
  const float* bias = (const float*)d_in[6];

  float* out   = (float*)d_out;              // [NN*DD]
  float* alpha = out + (size_t)NN * DD;      // [NE]

  char* p = (char*)d_ws;
  bf16*  hx      = (bf16*)p;    p += (size_t)RR * NN * DD * sizeof(bf16); // 76.8 MB
  float* nq      = (float*)p;   p += (size_t)RR * NN * sizeof(float);
  float* nk      = (float*)p;   p += (size_t)RR * NN * sizeof(float);
  float* wq      = (float*)p;   p += RR * DD * sizeof(float);
  float* wk      = (float*)p;   p += RR * DD * sizeof(float);
  int*   deg     = (int*)p;     p += NN * sizeof(int);
  int*   offs    = (int*)p;     p += NN * sizeof(int);
  float* mrec    = (float*)p;   p += NN * sizeof(float);
  float* irec    = (float*)p;   p += NN * sizeof(float);
  int*   bcnt    = (int*)p;     p += NB * sizeof(int);
  int*   bbase   = (int*)p;     p += NB * sizeof(int);
  int*   bcur    = (int*)p;     p += NB * sizeof(int);
  p = (char*)(((uintptr_t)p + 15) & ~(uintptr_t)15);
  unsigned* bedge = (unsigned*)p; p += (size_t)NE * sizeof(unsigned);     // 4.8 MB
  unsigned* rec  = (unsigned*)p;  p += (size_t)NE * sizeof(unsigned);     // 4.8 MB
  ushort* wp     = (ushort*)p;  p += (size_t)RR * 8 * 4 * 64 * 8 * sizeof(ushort); // 196 KB
  ushort* wp7    = (ushort*)p;  p += (size_t)4 * 64 * 8 * sizeof(ushort);          // 4 KB

  k_prep<<<49, 256, 0, stream>>>(W, qv, kv, wq, wk, wp, wp7, bcnt);
  k_gemm<<<(NN + 63) / 64, 256, 0, stream>>>(x, wp, wp7, (ushort*)hx, nq, nk);
  k_histb<<<(NE + 1023) / 1024, 256, 0, stream>>>(ei, bcnt);
  k_bscan<<<1, 64, 0, stream>>>(bcnt, bbase, bcur);
  k_bscatter<<<(NE + TILE - 1) / TILE, 256, 0, stream>>>(ei, et, bbase, bcur, bedge);
  k_bfinal<<<NB, 128, 0, stream>>>(bedge, bbase, bcnt, deg, offs, rec);
  k_agg<<<(NN + 7) / 8, 256, 0, stream>>>(x, bias, offs, deg, rec,
                                          nq, nk, hx, out, mrec, irec);
  k_alpha<<<(NE + 255) / 256, 256, 0, stream>>>(ei, et, nq, nk, mrec, irec, alpha);
}